// Round 6
// baseline (448.337 us; speedup 1.0000x reference)
//
#include <hip/hip_runtime.h>

#define BATCH 512
#define NNODE 200
#define CIN   200
#define HID   128
#define IPAD  232   // yT row stride in shorts: 464B rows, 16B-aligned, 2-way-max LDS banks
#define KCH   7     // 7 K-chunks of 32 (cover 224 >= 200)

typedef __attribute__((ext_vector_type(4))) float  f32x4;
typedef __attribute__((ext_vector_type(4))) int    i32x4;
typedef __attribute__((ext_vector_type(8))) short  sh8;
typedef __attribute__((ext_vector_type(4))) short  sh4;
typedef __attribute__((ext_vector_type(8))) __bf16 bf16x8;

__device__ __forceinline__ short f2bf(float x) {
  union { float f; unsigned u; } v; v.f = x;
  unsigned r = v.u + 0x7FFFu + ((v.u >> 16) & 1u);   // RNE
  return (short)(r >> 16);
}
__device__ __forceinline__ float bf2f(short s) {
  union { unsigned u; float f; } v; v.u = ((unsigned)(unsigned short)s) << 16;
  return v.f;
}
__device__ __forceinline__ f32x4 mfma16(sh8 a, sh8 b, f32x4 c) {
  return __builtin_amdgcn_mfma_f32_16x16x32_bf16(
      __builtin_bit_cast(bf16x8, a), __builtin_bit_cast(bf16x8, b), c, 0, 0, 0);
}
__device__ __forceinline__ f32x4 mfma16i(sh8 a, i32x4 b, f32x4 c) {
  return __builtin_amdgcn_mfma_f32_16x16x32_bf16(
      __builtin_bit_cast(bf16x8, a), __builtin_bit_cast(bf16x8, b), c, 0, 0, 0);
}
// expand 8 adjacency bits -> 4 dwords of packed {bf16(b_even), bf16(b_odd)}
__device__ __forceinline__ i32x4 expand8(unsigned byte_) {
  i32x4 w;
#pragma unroll
  for (int h = 0; h < 4; ++h) {
    unsigned p = byte_ >> (2 * h);
    unsigned d = ((p & 1u) ? 0x3F80u : 0u) | ((p & 2u) ? 0x3F800000u : 0u);
    w[h] = (int)d;
  }
  return w;
}

// ---------- K0: W1 [200][128] fp32 -> W1T [128][232] bf16 (cols [200,232) zeroed) ----------
__global__ void k_w1t(const float* __restrict__ W1, short* __restrict__ W1T) {
  int idx = blockIdx.x * 256 + threadIdx.x;
  if (idx < CIN * HID) {
    int c = idx >> 7, f = idx & 127;
    W1T[f * IPAD + c] = f2bf(W1[idx]);
  } else {
    int q = idx - CIN * HID;
    if (q < HID * (IPAD - CIN)) {
      int f = q / (IPAD - CIN), c = CIN + q % (IPAD - CIN);
      W1T[f * IPAD + c] = 0;
    }
  }
}

// ---------- K_main: one block per batch, 256 threads (4 waves). ----------
// phase 0: each lane packs ONE adj column (the one its wave consumes) into 7 bitmask VGPRs;
//          reads are row-coalesced, adj touched exactly once per block.
// phase A: yT = (x@W1)^T into LDS (MFMA).
// pass 1 : B-frags = shfl(bits) + VALU expand -> D[f][j]; h=relu(D+(1+e1)y+b1); g=h@W2.
// swap   : yT rows 0,1 <- g (bf16), rows 2..15 <- 0.
// pass 2 : D2[c][j] = sum_i g[c][i]*adj[i][j] from the same register bits; sum_j -> sums.
// epilog : out = b2 + ((1+e2)*sumg + sumagg)/N.
__global__ __launch_bounds__(256, 2) void k_main(const float* __restrict__ x,
                                                 const int* __restrict__ adj,
                                                 const short* __restrict__ W1T,
                                                 const float* __restrict__ b1,
                                                 const float* __restrict__ W2,
                                                 const float* __restrict__ b2,
                                                 const float* __restrict__ eps1p,
                                                 const float* __restrict__ eps2p,
                                                 float* __restrict__ out) {
  __shared__ short yT[HID][IPAD];   // 59,392 B
  __shared__ float gsm[2][NNODE];   //  1,600 B
  __shared__ float b1s[HID];        //    512 B
  __shared__ float W2s[HID][2];     //  1,024 B
  __shared__ float sums[4];         // 16 B -> total 62,544 B (2 blocks/CU)

  const int b = blockIdx.x, tid = threadIdx.x;
  const int wave = tid >> 6, lane = tid & 63, lq = lane >> 4, lm = lane & 15;

  // ---- init ----
  for (int i = tid; i < HID * 16; i += 256) {            // zero yT[:, 200:232)
    int f = i >> 4, o = i & 15;
    *(int*)&yT[f][200 + 2 * o] = 0;
  }
  if (tid < HID) { b1s[tid] = b1[tid]; W2s[tid][0] = W2[tid * 2]; W2s[tid][1] = W2[tid * 2 + 1]; }
  if (tid < 4) sums[tid] = 0.f;
  const float e1 = eps1p[0], e2 = eps2p[0];
  const float onep1 = 1.f + e1;

  // ---- phase 0: pack adjacency into per-lane register bitmasks ----
  // lane (wave, lq, lm) owns column jown = wave*16 + lq*64 + lm  (the column this wave's
  // jt = wave + 4*lq' tile, lane lm, will need -- fetched later via one shfl per word).
  const int* adjb = adj + (size_t)b * NNODE * NNODE;
  const int jown = wave * 16 + lq * 64 + lm;
  const int jclamp = min(jown, NNODE - 1);
  unsigned mbits[KCH];
  {
#pragma unroll
    for (int wd = 0; wd < 6; ++wd) {
      unsigned acc = 0;
#pragma unroll
      for (int t = 0; t < 32; ++t)
        acc |= (unsigned)(adjb[(wd * 32 + t) * NNODE + jclamp] & 1) << t;   // row-coalesced
      mbits[wd] = acc;
    }
    unsigned acc6 = 0;
#pragma unroll
    for (int t = 0; t < 8; ++t)
      acc6 |= (unsigned)(adjb[(192 + t) * NNODE + jclamp] & 1) << t;
    mbits[6] = acc6;
    if (jown >= NNODE) {
#pragma unroll
      for (int wd = 0; wd < KCH; ++wd) mbits[wd] = 0;    // zero cols j>=200
    }
  }

  // ---- phase A: yT = (x @ W1)^T into LDS ----
  const float* xb = x + (size_t)b * NNODE * CIN;
  for (int mt = wave; mt < 13; mt += 4) {
    const int Mbase = mt * 16;
    const int row = min(Mbase + lm, NNODE - 1);
    const float* xr = xb + (size_t)row * CIN;

    sh8 af[KCH];
#pragma unroll
    for (int k = 0; k < KCH; ++k) {
      const int c0 = k * 32 + lq * 8;
      f32x4 p0 = {0.f,0.f,0.f,0.f}, p1 = {0.f,0.f,0.f,0.f};
      if (c0 < CIN) { p0 = *(const f32x4*)(xr + c0); p1 = *(const f32x4*)(xr + c0 + 4); }
      sh8 a;
#pragma unroll
      for (int jj = 0; jj < 4; ++jj) { a[jj] = f2bf(p0[jj]); a[4 + jj] = f2bf(p1[jj]); }
      af[k] = a;
    }
    for (int ft = 0; ft < 8; ++ft) {
      const int fb = ft * 16;
      const short* wrow = W1T + (size_t)(fb + lm) * IPAD;
      f32x4 acc = {0.f,0.f,0.f,0.f};
#pragma unroll
      for (int k = 0; k < KCH; ++k)
        acc = mfma16(af[k], *(const sh8*)(wrow + k * 32 + lq * 8), acc);
      const int i0 = Mbase + lq * 4;                     // D: n=lm->f, m=lq*4+r->i
      if (i0 + 3 < NNODE) {
        sh4 st;
#pragma unroll
        for (int r = 0; r < 4; ++r) st[r] = f2bf(acc[r]);
        *(sh4*)&yT[fb + lm][i0] = st;
      }
    }
  }
  __syncthreads();

  // ---- pass 1 ----
  for (int jt = wave; jt < 13; jt += 4) {
    const int j = jt * 16 + lm;
    const bool jok = (j < NNODE);
    const int jc = min(j, NNODE - 1);
    const int src = (jt >> 2) * 16 + lm;                 // lane owning column j's bits

    i32x4 bfr[KCH];                                      // adjacency frags from register bits
#pragma unroll
    for (int k = 0; k < KCH; ++k) {
      unsigned bw = (unsigned)__shfl((int)mbits[k], src);
      bfr[k] = expand8((bw >> (lq * 8)) & 0xFFu);
    }

    float ga = 0.f, gb = 0.f;
    for (int ft = 0; ft < 8; ++ft) {
      const int fb = ft * 16;
      f32x4 acc = {0.f,0.f,0.f,0.f};
#pragma unroll
      for (int k = 0; k < KCH; ++k)
        acc = mfma16i(*(const sh8*)&yT[fb + lm][k * 32 + lq * 8], bfr[k], acc);
#pragma unroll
      for (int r = 0; r < 4; ++r) {
        const int f = fb + lq * 4 + r;                   // D[m=f][n=j]
        const float yself = bf2f(yT[f][jc]);             // (1+e1)*y self-term
        float h = fmaxf(acc[r] + onep1 * yself + b1s[f], 0.f);
        ga += h * W2s[f][0];
        gb += h * W2s[f][1];
      }
    }
    ga += __shfl_xor(ga, 16); ga += __shfl_xor(ga, 32);  // full f-sum: lanes<16 hold g[j]
    gb += __shfl_xor(gb, 16); gb += __shfl_xor(gb, 32);
    if (lane < 16 && jok) { gsm[0][j] = ga; gsm[1][j] = gb; }
    float ta = (lane < 16 && jok) ? ga : 0.f;            // once-per-tile sum(g)
    float tb = (lane < 16 && jok) ? gb : 0.f;
#pragma unroll
    for (int d = 1; d < 16; d <<= 1) { ta += __shfl_xor(ta, d); tb += __shfl_xor(tb, d); }
    if (lane == 0) { atomicAdd(&sums[0], ta); atomicAdd(&sums[1], tb); }
  }
  __syncthreads();

  // ---- swap: yT rows 0,1 <- g (bf16, cols>=200 zero); rows 2..15 <- 0 over cols [0,224) ----
  if (tid < 224) {
    yT[0][tid] = (tid < NNODE) ? f2bf(gsm[0][tid]) : (short)0;
    yT[1][tid] = (tid < NNODE) ? f2bf(gsm[1][tid]) : (short)0;
  }
  for (int i = tid; i < 14 * 112; i += 256) {
    int rr = i / 112, o = i % 112;
    *(int*)&yT[2 + rr][2 * o] = 0;
  }
  __syncthreads();

  // ---- pass 2: sum_j (adj^T g)_j from the same register bits ----
  for (int jt = wave; jt < 13; jt += 4) {
    const int j = jt * 16 + lm;
    const bool jok = (j < NNODE);
    const int src = (jt >> 2) * 16 + lm;
    f32x4 acc = {0.f,0.f,0.f,0.f};
#pragma unroll
    for (int k = 0; k < KCH; ++k) {
      unsigned bw = (unsigned)__shfl((int)mbits[k], src);
      i32x4 w = expand8((bw >> (lq * 8)) & 0xFFu);
      acc = mfma16i(*(const sh8*)&yT[lm][k * 32 + lq * 8], w, acc);  // A[m=c][k=i]
    }
    float v0 = (lq == 0 && jok) ? acc[0] : 0.f;          // D2[c=0][j=lm]
    float v1 = (lq == 0 && jok) ? acc[1] : 0.f;          // D2[c=1][j=lm]
#pragma unroll
    for (int d = 1; d < 16; d <<= 1) { v0 += __shfl_xor(v0, d); v1 += __shfl_xor(v1, d); }
    if (lane == 0) { atomicAdd(&sums[2], v0); atomicAdd(&sums[3], v1); }
  }
  __syncthreads();

  if (tid == 0) {
    out[b * 2 + 0] = b2[0] + ((1.f + e2) * sums[0] + sums[2]) * (1.f / NNODE);
    out[b * 2 + 1] = b2[1] + ((1.f + e2) * sums[1] + sums[3]) * (1.f / NNODE);
  }
}

extern "C" void kernel_launch(void* const* d_in, const int* in_sizes, int n_in,
                              void* d_out, int out_size, void* d_ws, size_t ws_size,
                              hipStream_t stream) {
  const float* x    = (const float*)d_in[0];
  const int*   adj  = (const int*)d_in[1];
  const float* W1   = (const float*)d_in[2];
  const float* b1   = (const float*)d_in[3];
  const float* W2   = (const float*)d_in[4];
  const float* b2   = (const float*)d_in[5];
  const float* eps1 = (const float*)d_in[6];
  const float* eps2 = (const float*)d_in[7];
  float* out = (float*)d_out;

  short* W1T = (short*)d_ws;                             // [128][232] bf16

  k_w1t <<<(HID * IPAD + 255) / 256, 256, 0, stream>>>(W1, W1T);
  k_main<<<BATCH, 256, 0, stream>>>(x, adj, W1T, b1, W2, b2, eps1, eps2, out);
}

// Round 7
// 276.782 us; speedup vs baseline: 1.6198x; 1.6198x over previous
//
#include <hip/hip_runtime.h>

#define BATCH 512
#define NNODE 200
#define CIN   200
#define HID   128
#define IPADY 224   // W1T / yT row stride (shorts): 448B rows, 16B-aligned
#define XPAD  204   // LDS x-tile row stride (floats): 816B, 16B-aligned, 2-way banks max
#define KCH   7     // 7 K-chunks of 32 (cover 224 >= 200)

typedef __attribute__((ext_vector_type(4))) float  f32x4;
typedef __attribute__((ext_vector_type(4))) int    i32x4;
typedef __attribute__((ext_vector_type(8))) short  sh8;
typedef __attribute__((ext_vector_type(4))) short  sh4;
typedef __attribute__((ext_vector_type(8))) __bf16 bf16x8;

__device__ __forceinline__ short f2bf(float x) {
  union { float f; unsigned u; } v; v.f = x;
  unsigned r = v.u + 0x7FFFu + ((v.u >> 16) & 1u);   // RNE
  return (short)(r >> 16);
}
__device__ __forceinline__ float bf2f(short s) {
  union { unsigned u; float f; } v; v.u = ((unsigned)(unsigned short)s) << 16;
  return v.f;
}
__device__ __forceinline__ f32x4 mfma16(sh8 a, sh8 b, f32x4 c) {
  return __builtin_amdgcn_mfma_f32_16x16x32_bf16(
      __builtin_bit_cast(bf16x8, a), __builtin_bit_cast(bf16x8, b), c, 0, 0, 0);
}
__device__ __forceinline__ f32x4 mfma16i(sh8 a, i32x4 b, f32x4 c) {
  return __builtin_amdgcn_mfma_f32_16x16x32_bf16(
      __builtin_bit_cast(bf16x8, a), __builtin_bit_cast(bf16x8, b), c, 0, 0, 0);
}
// expand 8 adjacency bits -> 4 dwords of packed {bf16(b_even)|bf16(b_odd)<<16}
__device__ __forceinline__ i32x4 expand8(unsigned byte_) {
  i32x4 w;
#pragma unroll
  for (int h = 0; h < 4; ++h) {
    unsigned p = byte_ >> (2 * h);
    unsigned d = ((p & 1u) ? 0x3F80u : 0u) | ((p & 2u) ? 0x3F800000u : 0u);
    w[h] = (int)d;
  }
  return w;
}

// ---------- K0: W1 [200][128] fp32 -> W1T [128][224] bf16 (cols [200,224) zeroed) ----------
__global__ void k_w1t(const float* __restrict__ W1, short* __restrict__ W1T) {
  int idx = blockIdx.x * 256 + threadIdx.x;
  if (idx < CIN * HID) {
    int c = idx >> 7, f = idx & 127;
    W1T[f * IPADY + c] = f2bf(W1[idx]);
  } else {
    int q = idx - CIN * HID;
    if (q < HID * (IPADY - CIN)) {
      int f = q / (IPADY - CIN), c = CIN + q % (IPADY - CIN);
      W1T[f * IPADY + c] = 0;
    }
  }
}

// ---------- K_pack: adj -> column bitmasks bits[b][j][8 words], word w bit t = adj[32w+t][j].
// Block (b, half). Thread j owns column j. half 0: rows 0..95 (words 0..2 + zero word 7);
// half 1: rows 96..199 (words 3..6). Row-coalesced reads (800B per i), no LDS, no atomics.
__global__ __launch_bounds__(256) void k_pack(const int* __restrict__ adj,
                                              unsigned* __restrict__ bits) {
  const int b = blockIdx.x >> 1, half = blockIdx.x & 1, j = threadIdx.x;
  const int* adjb = adj + (size_t)b * NNODE * NNODE;
  unsigned* bb = bits + (size_t)b * 224 * 8;
  if (j < NNODE) {
    if (half == 0) {
      unsigned w[3] = {0, 0, 0};
#pragma unroll
      for (int wd = 0; wd < 3; ++wd)
#pragma unroll
        for (int t = 0; t < 32; ++t)
          w[wd] |= (unsigned)(adjb[(wd * 32 + t) * NNODE + j] & 1) << t;
      bb[j * 8 + 0] = w[0]; bb[j * 8 + 1] = w[1]; bb[j * 8 + 2] = w[2]; bb[j * 8 + 7] = 0;
    } else {
      unsigned w[4] = {0, 0, 0, 0};
#pragma unroll
      for (int wd = 0; wd < 4; ++wd) {
        const int cnt = (wd < 3) ? 32 : 8;
#pragma unroll
        for (int t = 0; t < 32; ++t)
          if (t < cnt)
            w[wd] |= (unsigned)(adjb[(96 + wd * 32 + t) * NNODE + j] & 1) << t;
      }
      bb[j * 8 + 3] = w[0]; bb[j * 8 + 4] = w[1]; bb[j * 8 + 5] = w[2]; bb[j * 8 + 6] = w[3];
    }
  } else if (j < 224) {                                  // zero columns [200,224)
    if (half == 0) { bb[j*8+0] = 0; bb[j*8+1] = 0; bb[j*8+2] = 0; bb[j*8+7] = 0; }
    else           { bb[j*8+3] = 0; bb[j*8+4] = 0; bb[j*8+5] = 0; bb[j*8+6] = 0; }
  }
}

// ---------- K_y: yT[b][f][i] = (x@W1)^T. Block (b, g): stage 64 x-rows in LDS (coalesced),
// wave w computes mt = g*4+w. g==3 handles mt 12 (8 rows) + zeros yT cols [200,224).
__global__ __launch_bounds__(256) void k_y(const float* __restrict__ x,
                                           const short* __restrict__ W1T,
                                           short* __restrict__ yTws) {
  __shared__ float xs[64][XPAD];                         // 52,224 B -> 3 blocks/CU
  const int b = blockIdx.x >> 2, g = blockIdx.x & 3, tid = threadIdx.x;
  const int wave = tid >> 6, lane = tid & 63, lq = lane >> 4, lm = lane & 15;
  const int base = g * 64;
  const int nrow = (g < 3) ? 64 : 8;                     // g3: rows 192..199
  short* yb = yTws + (size_t)b * HID * IPADY;

  { // stage x rows [base, base+nrow): source is contiguous -> perfectly coalesced vec4 loads
    const f32x4* src = (const f32x4*)(x + (size_t)b * NNODE * CIN + (size_t)base * CIN);
    const int nv4 = nrow * 50;
    for (int idx = tid; idx < nv4; idx += 256) {
      int row = idx / 50, c4 = idx - row * 50;
      *(f32x4*)&xs[row][c4 * 4] = src[idx];
    }
  }
  if (g == 3) {                                          // zero yT cols [200,224): 128x12 ints
    for (int i = tid; i < HID * 12; i += 256) {
      int f = i / 12, o = i - f * 12;
      *(int*)&yb[f * IPADY + 200 + 2 * o] = 0;
    }
  }
  __syncthreads();

  if (g == 3 && wave != 0) return;                       // only mt 12 exists in g3
  const int mt = g * 4 + wave;
  const int Mbase = mt * 16;
  const int lr = min(wave * 16 + lm, nrow - 1);          // local staged row

  sh8 af[KCH];
#pragma unroll
  for (int k = 0; k < KCH; ++k) {
    const int c0 = k * 32 + lq * 8;
    const int cc = (c0 < CIN) ? c0 : 192;                // clamp: W1T rows are 0 for c>=200
    f32x4 p0 = *(const f32x4*)&xs[lr][cc];
    f32x4 p1 = *(const f32x4*)&xs[lr][cc + 4];
    sh8 a;
#pragma unroll
    for (int jj = 0; jj < 4; ++jj) { a[jj] = f2bf(p0[jj]); a[4 + jj] = f2bf(p1[jj]); }
    af[k] = a;
  }
  for (int ft = 0; ft < 8; ++ft) {
    const int fb = ft * 16;
    const short* wrow = W1T + (size_t)(fb + lm) * IPADY; // L2-resident (57 KB)
    f32x4 acc = {0.f,0.f,0.f,0.f};
#pragma unroll
    for (int k = 0; k < KCH; ++k)
      acc = mfma16(af[k], *(const sh8*)(wrow + k * 32 + lq * 8), acc);
    const int i0 = Mbase + lq * 4;                       // D: n=lm->f, m=lq*4+r->i
    if (i0 + 3 < NNODE) {
      sh4 st;
#pragma unroll
      for (int r = 0; r < 4; ++r) st[r] = f2bf(acc[r]);
      *(sh4*)&yb[(size_t)(fb + lm) * IPADY + i0] = st;
    }
  }
}

// ---------- K_gin2: one block per batch, 512 threads (8 waves), small LDS (R2 shape). ----------
// bits loaded once per wave (32B/lane), retained in regs across BOTH passes.
// pass 1: D[f][j] = sum_i yT[f][i]*adj[i][j] (yT via L2); h = relu(D + (1+e1)*yT[f][j] + b1);
//         g[j] = h@W2 fp32 -> gT (LDS, bf16) + tile sums.
// pass 2: D2[c][j] = sum_i gT[c][i]*adj[i][j] from register bits; sum_j -> sums[2..3].
// out = b2 + ((1+e2)*sumg + sumagg)/N.
__global__ __launch_bounds__(512) void k_gin2(const short* __restrict__ yTws,
                                              const unsigned* __restrict__ bits,
                                              const float* __restrict__ b1,
                                              const float* __restrict__ W2,
                                              const float* __restrict__ b2,
                                              const float* __restrict__ eps1p,
                                              const float* __restrict__ eps2p,
                                              float* __restrict__ out) {
  __shared__ short gT[16][232];     // 7,424 B (rows 0,1 = g; rest zero)
  __shared__ float b1s[HID];        //   512 B
  __shared__ float W2s[HID][2];     // 1,024 B
  __shared__ float sums[4];         // sumg0, sumg1, sumagg0, sumagg1

  const int b = blockIdx.x, tid = threadIdx.x;
  const int wave = tid >> 6, lane = tid & 63, lq = lane >> 4, lm = lane & 15;

  for (int i = tid; i < 16 * 232 / 2; i += 512) ((int*)gT)[i] = 0;
  if (tid < HID) { b1s[tid] = b1[tid]; W2s[tid][0] = W2[tid * 2]; W2s[tid][1] = W2[tid * 2 + 1]; }
  if (tid < 4) sums[tid] = 0.f;
  const float e1 = eps1p[0], e2 = eps2p[0];
  const float onep1 = 1.f + e1;
  __syncthreads();

  const short* yTb = yTws + (size_t)b * HID * IPADY;
  const unsigned* bb = bits + (size_t)b * 224 * 8;

  unsigned bw[2][8];                                     // column bits, kept for both passes
#pragma unroll
  for (int s = 0; s < 2; ++s) {
    const int jt = wave + 8 * s;
    if (jt < 13) {
      const unsigned* cp = bb + (size_t)(jt * 16 + lm) * 8;
      *(i32x4*)&bw[s][0] = *(const i32x4*)cp;
      *(i32x4*)&bw[s][4] = *(const i32x4*)(cp + 4);
    } else {
#pragma unroll
      for (int k = 0; k < 8; ++k) bw[s][k] = 0;
    }
  }

  // ---- pass 1 ----
#pragma unroll
  for (int s = 0; s < 2; ++s) {
    const int jt = wave + 8 * s;
    if (jt >= 13) continue;
    const int j = jt * 16 + lm;
    const bool jok = (j < NNODE);

    i32x4 bfr[KCH];
#pragma unroll
    for (int k = 0; k < KCH; ++k) bfr[k] = expand8((bw[s][k] >> (lq * 8)) & 0xFFu);

    float ga = 0.f, gb = 0.f;
    for (int ft = 0; ft < 8; ++ft) {
      const int fb = ft * 16;
      const short* yrow = yTb + (size_t)(fb + lm) * IPADY;
      f32x4 acc = {0.f,0.f,0.f,0.f};
#pragma unroll
      for (int k = 0; k < KCH; ++k)
        acc = mfma16i(*(const sh8*)(yrow + k * 32 + lq * 8), bfr[k], acc);
#pragma unroll
      for (int r = 0; r < 4; ++r) {
        const int f = fb + lq * 4 + r;                   // D[m=f][n=j]
        const float yself = bf2f(yTb[(size_t)f * IPADY + j]);  // j<224; cols>=200 are 0
        float h = fmaxf(acc[r] + onep1 * yself + b1s[f], 0.f);
        ga += h * W2s[f][0];
        gb += h * W2s[f][1];
      }
    }
    ga += __shfl_xor(ga, 16); ga += __shfl_xor(ga, 32);  // sum over lq -> full f-sum
    gb += __shfl_xor(gb, 16); gb += __shfl_xor(gb, 32);
    if (lane < 16 && jok) { gT[0][j] = f2bf(ga); gT[1][j] = f2bf(gb); }
    float ta = (lane < 16 && jok) ? ga : 0.f;
    float tb = (lane < 16 && jok) ? gb : 0.f;
#pragma unroll
    for (int d = 1; d < 16; d <<= 1) { ta += __shfl_xor(ta, d); tb += __shfl_xor(tb, d); }
    if (lane == 0) { atomicAdd(&sums[0], ta); atomicAdd(&sums[1], tb); }
  }
  __syncthreads();

  // ---- pass 2: sum_j (adj^T g)_j from retained register bits ----
#pragma unroll
  for (int s = 0; s < 2; ++s) {
    const int jt = wave + 8 * s;
    if (jt >= 13) continue;
    const int j = jt * 16 + lm;
    const bool jok = (j < NNODE);
    f32x4 acc = {0.f,0.f,0.f,0.f};
#pragma unroll
    for (int k = 0; k < KCH; ++k) {
      i32x4 w = expand8((bw[s][k] >> (lq * 8)) & 0xFFu);
      acc = mfma16i(*(const sh8*)&gT[lm][k * 32 + lq * 8], w, acc);  // A[m=c][k=i]
    }
    float v0 = (lq == 0 && jok) ? acc[0] : 0.f;          // D2[c=0][j]
    float v1 = (lq == 0 && jok) ? acc[1] : 0.f;          // D2[c=1][j]
#pragma unroll
    for (int d = 1; d < 16; d <<= 1) { v0 += __shfl_xor(v0, d); v1 += __shfl_xor(v1, d); }
    if (lane == 0) { atomicAdd(&sums[2], v0); atomicAdd(&sums[3], v1); }
  }
  __syncthreads();

  if (tid == 0) {
    out[b * 2 + 0] = b2[0] + ((1.f + e2) * sums[0] + sums[2]) * (1.f / NNODE);
    out[b * 2 + 1] = b2[1] + ((1.f + e2) * sums[1] + sums[3]) * (1.f / NNODE);
  }
}

extern "C" void kernel_launch(void* const* d_in, const int* in_sizes, int n_in,
                              void* d_out, int out_size, void* d_ws, size_t ws_size,
                              hipStream_t stream) {
  const float* x    = (const float*)d_in[0];
  const int*   adj  = (const int*)d_in[1];
  const float* W1   = (const float*)d_in[2];
  const float* b1   = (const float*)d_in[3];
  const float* W2   = (const float*)d_in[4];
  const float* b2   = (const float*)d_in[5];
  const float* eps1 = (const float*)d_in[6];
  const float* eps2 = (const float*)d_in[7];
  float* out = (float*)d_out;

  short*    W1T  = (short*)d_ws;                               // 57,344 B
  unsigned* bitsp = (unsigned*)((char*)d_ws + 64 * 1024);      // [512][224][8] = 3.7 MB
  short*    yT   = (short*)((char*)d_ws + 4 * 1024 * 1024);    // [512][128][224] = 29.4 MB

  k_w1t <<<(HID * IPADY + 255) / 256, 256, 0, stream>>>(W1, W1T);
  k_pack<<<BATCH * 2, 256, 0, stream>>>(adj, bitsp);
  k_y   <<<BATCH * 4, 256, 0, stream>>>(x, W1T, yT);
  k_gin2<<<BATCH, 512, 0, stream>>>(yT, bitsp, b1, W2, b2, eps1, eps2, out);
}

// Round 8
// 268.486 us; speedup vs baseline: 1.6699x; 1.0309x over previous
//
#include <hip/hip_runtime.h>

#define BATCH 512
#define NNODE 200
#define CIN   200
#define HID   128
#define IPADY 224   // W1T / yT row stride (shorts): 448B rows, 16B-aligned
#define KCH   7     // 7 K-chunks of 32 (cover 224 >= 200)

typedef __attribute__((ext_vector_type(4))) float  f32x4;
typedef __attribute__((ext_vector_type(4))) int    i32x4;
typedef __attribute__((ext_vector_type(8))) short  sh8;
typedef __attribute__((ext_vector_type(4))) short  sh4;
typedef __attribute__((ext_vector_type(8))) __bf16 bf16x8;

__device__ __forceinline__ short f2bf(float x) {
  union { float f; unsigned u; } v; v.f = x;
  unsigned r = v.u + 0x7FFFu + ((v.u >> 16) & 1u);   // RNE
  return (short)(r >> 16);
}
__device__ __forceinline__ float bf2f(short s) {
  union { unsigned u; float f; } v; v.u = ((unsigned)(unsigned short)s) << 16;
  return v.f;
}
__device__ __forceinline__ f32x4 mfma16(sh8 a, sh8 b, f32x4 c) {
  return __builtin_amdgcn_mfma_f32_16x16x32_bf16(
      __builtin_bit_cast(bf16x8, a), __builtin_bit_cast(bf16x8, b), c, 0, 0, 0);
}
__device__ __forceinline__ f32x4 mfma16i(sh8 a, i32x4 b, f32x4 c) {
  return __builtin_amdgcn_mfma_f32_16x16x32_bf16(
      __builtin_bit_cast(bf16x8, a), __builtin_bit_cast(bf16x8, b), c, 0, 0, 0);
}
// expand 8 adjacency bits -> 4 dwords of packed {bf16(b_even)|bf16(b_odd)<<16}
__device__ __forceinline__ i32x4 expand8(unsigned byte_) {
  i32x4 w;
#pragma unroll
  for (int h = 0; h < 4; ++h) {
    unsigned p = byte_ >> (2 * h);
    unsigned d = ((p & 1u) ? 0x3F80u : 0u) | ((p & 2u) ? 0x3F800000u : 0u);
    w[h] = (int)d;
  }
  return w;
}

// ---------- K0: W1 [200][128] fp32 -> W1T [128][224] bf16 (cols [200,224) zeroed) ----------
__global__ void k_w1t(const float* __restrict__ W1, short* __restrict__ W1T) {
  int idx = blockIdx.x * 256 + threadIdx.x;
  if (idx < CIN * HID) {
    int c = idx >> 7, f = idx & 127;
    W1T[f * IPADY + c] = f2bf(W1[idx]);
  } else {
    int q = idx - CIN * HID;
    if (q < HID * (IPADY - CIN)) {
      int f = q / (IPADY - CIN), c = CIN + q % (IPADY - CIN);
      W1T[f * IPADY + c] = 0;
    }
  }
}

// ---------- K_pack: adj -> column bitmasks bits[b][j][8 words]; bit t of word w = adj[32w+t][j].
// Block (b, half); thread j owns column j; reads row-coalesced; columns [200,224) zeroed.
__global__ __launch_bounds__(256) void k_pack(const int* __restrict__ adj,
                                              unsigned* __restrict__ bits) {
  const int b = blockIdx.x >> 1, half = blockIdx.x & 1, j = threadIdx.x;
  const int* adjb = adj + (size_t)b * NNODE * NNODE;
  unsigned* bb = bits + (size_t)b * 224 * 8;
  if (j < NNODE) {
    if (half == 0) {
      unsigned w[3] = {0, 0, 0};
#pragma unroll
      for (int wd = 0; wd < 3; ++wd)
#pragma unroll
        for (int t = 0; t < 32; ++t)
          w[wd] |= (unsigned)(adjb[(wd * 32 + t) * NNODE + j] & 1) << t;
      bb[j * 8 + 0] = w[0]; bb[j * 8 + 1] = w[1]; bb[j * 8 + 2] = w[2]; bb[j * 8 + 7] = 0;
    } else {
      unsigned w[4] = {0, 0, 0, 0};
#pragma unroll
      for (int wd = 0; wd < 4; ++wd) {
        const int cnt = (wd < 3) ? 32 : 8;
#pragma unroll
        for (int t = 0; t < 32; ++t)
          if (t < cnt)
            w[wd] |= (unsigned)(adjb[(96 + wd * 32 + t) * NNODE + j] & 1) << t;
      }
      bb[j * 8 + 3] = w[0]; bb[j * 8 + 4] = w[1]; bb[j * 8 + 5] = w[2]; bb[j * 8 + 6] = w[3];
    }
  } else if (j < 224) {
    if (half == 0) { bb[j*8+0] = 0; bb[j*8+1] = 0; bb[j*8+2] = 0; bb[j*8+7] = 0; }
    else           { bb[j*8+3] = 0; bb[j*8+4] = 0; bb[j*8+5] = 0; bb[j*8+6] = 0; }
  }
}

// ---------- K_y: one wave per (b,mt). No LDS, no barriers. x reads ~96% coalesced
// (per k-chunk a wave covers 16 rows x 128 contiguous bytes). yT pad cols [200,224)
// carry junk -- annihilated by zero bits in k_agg/k_fin.
__global__ __launch_bounds__(256) void k_y(const float* __restrict__ x,
                                           const short* __restrict__ W1T,
                                           short* __restrict__ yTws) {
  const int wave = threadIdx.x >> 6, lane = threadIdx.x & 63;
  const int wid = blockIdx.x * 4 + wave;                 // 0..6655
  const int b = wid / 13, mt = wid - b * 13;
  const int lq = lane >> 4, lm = lane & 15;

  const float* xr = x + (size_t)b * NNODE * CIN + (size_t)min(mt * 16 + lm, NNODE - 1) * CIN;
  short* yb = yTws + (size_t)b * HID * IPADY;

  sh8 af[KCH];                                           // A-frags held across f-tiles
#pragma unroll
  for (int k = 0; k < KCH; ++k) {
    const int c0 = k * 32 + lq * 8;
    f32x4 p0 = {0.f,0.f,0.f,0.f}, p1 = {0.f,0.f,0.f,0.f};
    if (c0 < CIN) { p0 = *(const f32x4*)(xr + c0); p1 = *(const f32x4*)(xr + c0 + 4); }
    sh8 a;
#pragma unroll
    for (int jj = 0; jj < 4; ++jj) { a[jj] = f2bf(p0[jj]); a[4 + jj] = f2bf(p1[jj]); }
    af[k] = a;
  }
  for (int ft = 0; ft < 8; ++ft) {
    const int fb = ft * 16;
    const short* wrow = W1T + (size_t)(fb + lm) * IPADY; // L2-resident (57 KB)
    f32x4 acc = {0.f,0.f,0.f,0.f};
#pragma unroll
    for (int k = 0; k < KCH; ++k)
      acc = mfma16(af[k], *(const sh8*)(wrow + k * 32 + lq * 8), acc);
    sh4 st;                                              // D: n=lm->f, m=lq*4+r->i
#pragma unroll
    for (int r = 0; r < 4; ++r) st[r] = f2bf(acc[r]);
    *(sh4*)&yb[(size_t)(fb + lm) * IPADY + mt * 16 + lq * 4] = st;  // max col 207 < 224
  }
}

// ---------- K_agg: one wave per (b,jt). No LDS, no barriers, no atomics. ----------
// D[f][j] = sum_i yT[f][i]*adj[i][j]; h = relu(D + (1+e1)*yT[f][j] + b1); g=h@W2 -> gws bf16.
__global__ __launch_bounds__(256) void k_agg(const short* __restrict__ yTws,
                                             const unsigned* __restrict__ bits,
                                             const float* __restrict__ b1,
                                             const float* __restrict__ W2,
                                             const float* __restrict__ eps1p,
                                             short* __restrict__ gws) {
  const int wave = threadIdx.x >> 6, lane = threadIdx.x & 63;
  const int wid = blockIdx.x * 4 + wave;                 // 0..6655
  const int b = wid / 13, jt = wid - b * 13;
  const int lq = lane >> 4, lm = lane & 15;
  const int j = jt * 16 + lm;
  const bool jok = (j < NNODE);
  const float onep1 = 1.f + eps1p[0];

  const short* yTb = yTws + (size_t)b * HID * IPADY;
  const unsigned* cp = bits + (size_t)b * 224 * 8 + (size_t)j * 8;   // j<224 in-bounds
  unsigned bwa[8];
  *(i32x4*)&bwa[0] = *(const i32x4*)cp;
  *(i32x4*)&bwa[4] = *(const i32x4*)(cp + 4);

  i32x4 bfr[KCH];
#pragma unroll
  for (int k = 0; k < KCH; ++k) bfr[k] = expand8((bwa[k] >> (lq * 8)) & 0xFFu);

  float ga = 0.f, gb = 0.f;
  for (int ft = 0; ft < 8; ++ft) {
    const int fb = ft * 16;
    const short* yrow = yTb + (size_t)(fb + lm) * IPADY;
    f32x4 acc = {0.f,0.f,0.f,0.f};
#pragma unroll
    for (int k = 0; k < KCH; ++k)
      acc = mfma16i(*(const sh8*)(yrow + k * 32 + lq * 8), bfr[k], acc);
#pragma unroll
    for (int r = 0; r < 4; ++r) {
      const int f = fb + lq * 4 + r;                     // D[m=f][n=j]
      const float yself = jok ? bf2f(yTb[(size_t)f * IPADY + j]) : 0.f;
      float h = fmaxf(acc[r] + onep1 * yself + b1[f], 0.f);
      ga += h * W2[f * 2];
      gb += h * W2[f * 2 + 1];
    }
  }
  ga += __shfl_xor(ga, 16); ga += __shfl_xor(ga, 32);    // sum lq groups -> full f-sum
  gb += __shfl_xor(gb, 16); gb += __shfl_xor(gb, 32);
  if (lane < 16 && jok) {
    gws[(size_t)b * 448 + j]       = f2bf(ga);
    gws[(size_t)b * 448 + 224 + j] = f2bf(gb);
  }
}

// ---------- K_fin: per-batch epilogue. sumg + sumagg (= sum_j (adj^T g)_j via MFMA). ----------
__global__ __launch_bounds__(256) void k_fin(const short* __restrict__ gws,
                                             const unsigned* __restrict__ bits,
                                             const float* __restrict__ b2,
                                             const float* __restrict__ eps2p,
                                             float* __restrict__ out) {
  __shared__ short gT[16][232];     // rows 0,1 = g; rows 2..15 zero
  __shared__ float red[4][4];       // per-wave {sg0, sg1, a0, a1}
  const int b = blockIdx.x, tid = threadIdx.x;
  const int wave = tid >> 6, lane = tid & 63, lq = lane >> 4, lm = lane & 15;

  for (int i = tid; i < 16 * 232 / 2; i += 256) ((int*)gT)[i] = 0;
  __syncthreads();
  if (tid < NNODE) {
    gT[0][tid] = gws[(size_t)b * 448 + tid];
    gT[1][tid] = gws[(size_t)b * 448 + 224 + tid];
  }
  __syncthreads();

  // sumg (per-wave butterfly over lanes; tid>=200 contribute 0)
  float sg0 = 0.f, sg1 = 0.f;
  if (tid < NNODE) { sg0 = bf2f(gT[0][tid]); sg1 = bf2f(gT[1][tid]); }
#pragma unroll
  for (int d = 1; d < 64; d <<= 1) { sg0 += __shfl_xor(sg0, d); sg1 += __shfl_xor(sg1, d); }

  // sumagg: wave handles jt = wave, wave+4, wave+8, wave+12
  float a0 = 0.f, a1 = 0.f;
  const unsigned* bb = bits + (size_t)b * 224 * 8;
  for (int jt = wave; jt < 13; jt += 4) {
    const int j = jt * 16 + lm;
    const bool jok = (j < NNODE);
    const unsigned* cp = bb + (size_t)j * 8;
    unsigned bwa[8];
    *(i32x4*)&bwa[0] = *(const i32x4*)cp;
    *(i32x4*)&bwa[4] = *(const i32x4*)(cp + 4);
    f32x4 acc = {0.f,0.f,0.f,0.f};
#pragma unroll
    for (int k = 0; k < KCH; ++k) {
      i32x4 w = expand8((bwa[k] >> (lq * 8)) & 0xFFu);
      acc = mfma16i(*(const sh8*)&gT[lm][k * 32 + lq * 8], w, acc);  // A[m=c][k=i]
    }
    float v0 = (lq == 0 && jok) ? acc[0] : 0.f;          // D2[c=0][j]
    float v1 = (lq == 0 && jok) ? acc[1] : 0.f;
#pragma unroll
    for (int d = 1; d < 16; d <<= 1) { v0 += __shfl_xor(v0, d); v1 += __shfl_xor(v1, d); }
    a0 += v0; a1 += v1;                                  // lane 0 holds tile sums
  }
  if (lane == 0) { red[wave][0] = sg0; red[wave][1] = sg1; red[wave][2] = a0; red[wave][3] = a1; }
  __syncthreads();

  if (tid == 0) {
    const float e2 = eps2p[0];
    float SG0 = 0.f, SG1 = 0.f, A0 = 0.f, A1 = 0.f;
#pragma unroll
    for (int w = 0; w < 4; ++w) { SG0 += red[w][0]; SG1 += red[w][1]; A0 += red[w][2]; A1 += red[w][3]; }
    out[b * 2 + 0] = b2[0] + ((1.f + e2) * SG0 + A0) * (1.f / NNODE);
    out[b * 2 + 1] = b2[1] + ((1.f + e2) * SG1 + A1) * (1.f / NNODE);
  }
}

extern "C" void kernel_launch(void* const* d_in, const int* in_sizes, int n_in,
                              void* d_out, int out_size, void* d_ws, size_t ws_size,
                              hipStream_t stream) {
  const float* x    = (const float*)d_in[0];
  const int*   adj  = (const int*)d_in[1];
  const float* W1   = (const float*)d_in[2];
  const float* b1   = (const float*)d_in[3];
  const float* W2   = (const float*)d_in[4];
  const float* b2   = (const float*)d_in[5];
  const float* eps1 = (const float*)d_in[6];
  const float* eps2 = (const float*)d_in[7];
  float* out = (float*)d_out;

  short*    W1T   = (short*)d_ws;                              // 57,344 B
  unsigned* bitsp = (unsigned*)((char*)d_ws + (64 << 10));     // [512][224][8] = 3.67 MB
  short*    yT    = (short*)((char*)d_ws + (4 << 20));         // [512][128][224] = 29.4 MB
  short*    gws   = (short*)((char*)d_ws + (36 << 20));        // [512][2][224] bf16 = 459 KB

  k_w1t <<<(HID * IPADY + 255) / 256, 256, 0, stream>>>(W1, W1T);
  k_pack<<<BATCH * 2, 256, 0, stream>>>(adj, bitsp);
  k_y   <<<(BATCH * 13) / 4, 256, 0, stream>>>(x, W1T, yT);
  k_agg <<<(BATCH * 13) / 4, 256, 0, stream>>>(yT, bitsp, b1, W2, eps1, gws);
  k_fin <<<BATCH, 256, 0, stream>>>(gws, bitsp, b2, eps2, out);
}

// Round 9
// 267.885 us; speedup vs baseline: 1.6736x; 1.0022x over previous
//
#include <hip/hip_runtime.h>

#define BATCH 512
#define NNODE 200
#define CIN   200
#define HID   128
#define IPADY 224   // W1T / yT row stride (shorts): 448B rows, 16B-aligned
#define KCH   7     // 7 K-chunks of 32 (cover 224 >= 200)

typedef __attribute__((ext_vector_type(4))) float  f32x4;
typedef __attribute__((ext_vector_type(4))) int    i32x4;
typedef __attribute__((ext_vector_type(8))) short  sh8;
typedef __attribute__((ext_vector_type(4))) short  sh4;
typedef __attribute__((ext_vector_type(8))) __bf16 bf16x8;

__device__ __forceinline__ short f2bf(float x) {
  union { float f; unsigned u; } v; v.f = x;
  unsigned r = v.u + 0x7FFFu + ((v.u >> 16) & 1u);   // RNE
  return (short)(r >> 16);
}
__device__ __forceinline__ f32x4 mfma16(sh8 a, sh8 b, f32x4 c) {
  return __builtin_amdgcn_mfma_f32_16x16x32_bf16(
      __builtin_bit_cast(bf16x8, a), __builtin_bit_cast(bf16x8, b), c, 0, 0, 0);
}
__device__ __forceinline__ f32x4 mfma16i(sh8 a, i32x4 b, f32x4 c) {
  return __builtin_amdgcn_mfma_f32_16x16x32_bf16(
      __builtin_bit_cast(bf16x8, a), __builtin_bit_cast(bf16x8, b), c, 0, 0, 0);
}
// expand 8 adjacency bits -> 4 dwords of packed {bf16(b_even)|bf16(b_odd)<<16}
__device__ __forceinline__ i32x4 expand8(unsigned byte_) {
  i32x4 w;
#pragma unroll
  for (int h = 0; h < 4; ++h) {
    unsigned p = byte_ >> (2 * h);
    unsigned d = ((p & 1u) ? 0x3F80u : 0u) | ((p & 2u) ? 0x3F800000u : 0u);
    w[h] = (int)d;
  }
  return w;
}

// ---------- K_prep: all independent preprocessing in one launch ----------
// blocks [0,112)      : W1 -> W1T bf16 transpose (+ blocks 0..3: out[i] = b2[i&1])
// blocks [112,1136)   : adj -> column bitmasks bits[b][j][8]; (b = (blk-112)>>1, half)
// blocks [1136,1648)  : deg[b][i] = sum_j adj[b][i][j] (fp32), rows L3-hot
__global__ __launch_bounds__(256) void k_prep(const float* __restrict__ W1,
                                              const int* __restrict__ adj,
                                              const float* __restrict__ b2,
                                              short* __restrict__ W1T,
                                              unsigned* __restrict__ bits,
                                              float* __restrict__ deg,
                                              float* __restrict__ out) {
  const int blk = blockIdx.x, tid = threadIdx.x;
  if (blk < 112) {
    const int idx = blk * 256 + tid;                     // [0, 28672) = 128*224
    if (idx < 2 * BATCH) out[idx] = b2[idx & 1];         // init out = b2
    if (idx < CIN * HID) {
      int c = idx >> 7, f = idx & 127;
      W1T[f * IPADY + c] = f2bf(W1[idx]);                // coalesced W1 read
    } else {
      int q = idx - CIN * HID;                           // [0, 3072) = 128*24
      int f = q / 24, c = CIN + q % 24;
      W1T[f * IPADY + c] = 0;
    }
  } else if (blk < 1136) {
    const int bb_ = blk - 112;
    const int b = bb_ >> 1, half = bb_ & 1, j = tid;
    const int* adjb = adj + (size_t)b * NNODE * NNODE;
    unsigned* bb = bits + (size_t)b * 224 * 8;
    if (j < NNODE) {
      if (half == 0) {
        unsigned w[3] = {0, 0, 0};
#pragma unroll
        for (int wd = 0; wd < 3; ++wd)
#pragma unroll
          for (int t = 0; t < 32; ++t)
            w[wd] |= (unsigned)(adjb[(wd * 32 + t) * NNODE + j] & 1) << t;
        bb[j * 8 + 0] = w[0]; bb[j * 8 + 1] = w[1]; bb[j * 8 + 2] = w[2]; bb[j * 8 + 7] = 0;
      } else {
        unsigned w[4] = {0, 0, 0, 0};
#pragma unroll
        for (int wd = 0; wd < 4; ++wd) {
          const int cnt = (wd < 3) ? 32 : 8;
#pragma unroll
          for (int t = 0; t < 32; ++t)
            if (t < cnt)
              w[wd] |= (unsigned)(adjb[(96 + wd * 32 + t) * NNODE + j] & 1) << t;
        }
        bb[j * 8 + 3] = w[0]; bb[j * 8 + 4] = w[1]; bb[j * 8 + 5] = w[2]; bb[j * 8 + 6] = w[3];
      }
    } else if (j < 224) {
      if (half == 0) { bb[j*8+0] = 0; bb[j*8+1] = 0; bb[j*8+2] = 0; bb[j*8+7] = 0; }
      else           { bb[j*8+3] = 0; bb[j*8+4] = 0; bb[j*8+5] = 0; bb[j*8+6] = 0; }
    }
  } else {
    const int b = blk - 1136;
    if (tid < NNODE) {                                   // thread i: contiguous 800B row sum
      const int* rowp = adj + (size_t)b * NNODE * NNODE + (size_t)tid * NNODE;
      int s = 0;
#pragma unroll 10
      for (int q = 0; q < 50; ++q) {
        i32x4 v = *(const i32x4*)(rowp + q * 4);
        s += v[0] + v[1] + v[2] + v[3];
      }
      deg[b * 224 + tid] = (float)s;
    } else if (tid < 224) {
      deg[b * 224 + tid] = 0.f;
    }
  }
}

// ---------- K_y: one wave per (b,mt). No LDS/barriers; 128-VGPR budget, ft unroll-2. ----------
__global__ __launch_bounds__(256, 4) void k_y(const float* __restrict__ x,
                                              const short* __restrict__ W1T,
                                              short* __restrict__ yTws) {
  const int wave = threadIdx.x >> 6, lane = threadIdx.x & 63;
  const int wid = blockIdx.x * 4 + wave;                 // 0..6655
  const int b = wid / 13, mt = wid - b * 13;
  const int lq = lane >> 4, lm = lane & 15;

  const float* xr = x + (size_t)b * NNODE * CIN + (size_t)min(mt * 16 + lm, NNODE - 1) * CIN;
  short* yb = yTws + (size_t)b * HID * IPADY;

  sh8 af[KCH];                                           // A-frags held across f-tiles
#pragma unroll
  for (int k = 0; k < KCH; ++k) {
    const int c0 = k * 32 + lq * 8;
    f32x4 p0 = {0.f,0.f,0.f,0.f}, p1 = {0.f,0.f,0.f,0.f};
    if (c0 < CIN) { p0 = *(const f32x4*)(xr + c0); p1 = *(const f32x4*)(xr + c0 + 4); }
    sh8 a;
#pragma unroll
    for (int jj = 0; jj < 4; ++jj) { a[jj] = f2bf(p0[jj]); a[4 + jj] = f2bf(p1[jj]); }
    af[k] = a;
  }
#pragma unroll 2
  for (int ft = 0; ft < 8; ++ft) {
    const int fb = ft * 16;
    const short* wrow = W1T + (size_t)(fb + lm) * IPADY; // L2-resident (57 KB)
    f32x4 acc = {0.f,0.f,0.f,0.f};
#pragma unroll
    for (int k = 0; k < KCH; ++k)
      acc = mfma16(af[k], *(const sh8*)(wrow + k * 32 + lq * 8), acc);
    sh4 st;                                              // D: n=lm->f, m=lq*4+r->i
#pragma unroll
    for (int r = 0; r < 4; ++r) st[r] = f2bf(acc[r]);
    *(sh4*)&yb[(size_t)(fb + lm) * IPADY + mt * 16 + lq * 4] = st;  // max col 207 < 224
  }
}

// ---------- K_agg: one wave per (b,jt). Computes g AND its contribution to out. ----------
// frag = adj bits + (1+e1) diag (cndmask patch). D[f][j] -> h=relu(D+b1) -> g=h@W2 (fp32).
// tile sum t = sum_j (1+e2+deg_j)*g_j ; atomicAdd(out[b], t/N). No LDS, no second pass.
__global__ __launch_bounds__(256, 4) void k_agg(const short* __restrict__ yTws,
                                                const unsigned* __restrict__ bits,
                                                const float* __restrict__ b1,
                                                const float* __restrict__ W2,
                                                const float* __restrict__ degp,
                                                const float* __restrict__ eps1p,
                                                const float* __restrict__ eps2p,
                                                float* __restrict__ out) {
  const int wave = threadIdx.x >> 6, lane = threadIdx.x & 63;
  const int wid = blockIdx.x * 4 + wave;                 // 0..6655
  const int b = wid / 13, jt = wid - b * 13;
  const int lq = lane >> 4, lm = lane & 15;
  const int j = jt * 16 + lm;
  const bool jok = (j < NNODE);
  const float e1 = eps1p[0], e2 = eps2p[0];
  const unsigned cd0 = (unsigned)(unsigned short)f2bf(1.f + e1);   // diag, bit==0
  const unsigned cd1 = (unsigned)(unsigned short)f2bf(2.f + e1);   // diag, bit==1

  const short* yTb = yTws + (size_t)b * HID * IPADY;
  const unsigned* cp = bits + (size_t)b * 224 * 8 + (size_t)j * 8; // j<=207 in-bounds
  unsigned bwa[8];
  *(i32x4*)&bwa[0] = *(const i32x4*)cp;
  *(i32x4*)&bwa[4] = *(const i32x4*)(cp + 4);

  i32x4 bfr[KCH];                                        // adjacency + diagonal fragments
#pragma unroll
  for (int k = 0; k < KCH; ++k) {
    const unsigned byte_ = (bwa[k] >> (lq * 8)) & 0xFFu;
    i32x4 w = expand8(byte_);
    const int d = j - (k * 32 + lq * 8);                 // diag position within this byte
    if (d >= 0 && d < 8) {
      const unsigned val = ((byte_ >> d) & 1u) ? cd1 : cd0;
      const int h2 = d >> 1, sh = (d & 1) * 16;
      w[h2] = (int)(((unsigned)w[h2] & ~(0xFFFFu << sh)) | (val << sh));
    }
    bfr[k] = w;
  }

  float ga = 0.f, gb = 0.f;
#pragma unroll 2
  for (int ft = 0; ft < 8; ++ft) {
    const int fb = ft * 16;
    const short* yrow = yTb + (size_t)(fb + lm) * IPADY;
    f32x4 acc = {0.f,0.f,0.f,0.f};
#pragma unroll
    for (int k = 0; k < KCH; ++k)
      acc = mfma16i(*(const sh8*)(yrow + k * 32 + lq * 8), bfr[k], acc);
    const f32x4 b1v = *(const f32x4*)(b1 + fb + lq * 4);           // f = fb+lq*4+r
    const f32x4 w2a = *(const f32x4*)(W2 + (fb + lq * 4) * 2);     // f0c0 f0c1 f1c0 f1c1
    const f32x4 w2b = *(const f32x4*)(W2 + (fb + lq * 4) * 2 + 4); // f2c0 f2c1 f3c0 f3c1
#pragma unroll
    for (int r = 0; r < 4; ++r) {
      const float h = fmaxf(acc[r] + b1v[r], 0.f);
      const float wc0 = (r == 0) ? w2a[0] : (r == 1) ? w2a[2] : (r == 2) ? w2b[0] : w2b[2];
      const float wc1 = (r == 0) ? w2a[1] : (r == 1) ? w2a[3] : (r == 2) ? w2b[1] : w2b[3];
      ga += h * wc0;
      gb += h * wc1;
    }
  }
  ga += __shfl_xor(ga, 16); ga += __shfl_xor(ga, 32);    // full f-sum -> every lane has g[j=lm]
  gb += __shfl_xor(gb, 16); gb += __shfl_xor(gb, 32);

  const float w = 1.f + e2 + degp[b * 224 + j];          // 4-way broadcast load (j<=207)
  float t0 = jok ? w * ga : 0.f;
  float t1 = jok ? w * gb : 0.f;
#pragma unroll
  for (int d = 1; d < 16; d <<= 1) { t0 += __shfl_xor(t0, d); t1 += __shfl_xor(t1, d); }
  if (lane == 0) {
    atomicAdd(&out[b * 2 + 0], t0 * (1.f / NNODE));      // 13 adders per address
    atomicAdd(&out[b * 2 + 1], t1 * (1.f / NNODE));
  }
}

extern "C" void kernel_launch(void* const* d_in, const int* in_sizes, int n_in,
                              void* d_out, int out_size, void* d_ws, size_t ws_size,
                              hipStream_t stream) {
  const float* x    = (const float*)d_in[0];
  const int*   adj  = (const int*)d_in[1];
  const float* W1   = (const float*)d_in[2];
  const float* b1   = (const float*)d_in[3];
  const float* W2   = (const float*)d_in[4];
  const float* b2   = (const float*)d_in[5];
  const float* eps1 = (const float*)d_in[6];
  const float* eps2 = (const float*)d_in[7];
  float* out = (float*)d_out;

  short*    W1T   = (short*)d_ws;                              // 57,344 B
  unsigned* bitsp = (unsigned*)((char*)d_ws + (64 << 10));     // [512][224][8] = 3.67 MB
  short*    yT    = (short*)((char*)d_ws + (4 << 20));         // [512][128][224] = 29.4 MB
  float*    degp  = (float*)((char*)d_ws + (36 << 20));        // [512][224] fp32 = 459 KB

  k_prep<<<1648, 256, 0, stream>>>(W1, adj, b2, W1T, bitsp, degp, out);
  k_y   <<<(BATCH * 13) / 4, 256, 0, stream>>>(x, W1T, yT);
  k_agg <<<(BATCH * 13) / 4, 256, 0, stream>>>(yT, bitsp, b1, W2, degp, eps1, eps2, out);
}